// Round 1
// baseline (314.641 us; speedup 1.0000x reference)
//
#include <hip/hip_runtime.h>

// Connected-component labeling, 8-connectivity, 2048x2048 binary mask
// (prob > 0.5). Output: int32, (component min flat index)+1 for fg, 0 for bg.
// Algorithm: lock-free union-find with atomicMin (union-by-min), whose final
// roots are exactly the component minima -> bit-identical to the reference.

#define H 2048
#define W 2048
#define NPIX (H * W)

__device__ __forceinline__ int find_root(const int* __restrict__ L, int a) {
    int n = L[a];
    while (n != a) {
        a = n;
        n = L[a];
    }
    return a;
}

__device__ __forceinline__ void unite(int* L, int a, int b) {
    while (true) {
        a = find_root(L, a);
        b = find_root(L, b);
        if (a == b) return;
        if (a > b) { int t = a; a = b; b = t; }
        // attach larger root under smaller
        int old = atomicMin(&L[b], a);
        if (old == b) return;  // successfully attached
        b = old;               // someone raced; retry from the value we saw
    }
}

__global__ void k_init(const float* __restrict__ prob, int* __restrict__ lab) {
    int i = blockIdx.x * blockDim.x + threadIdx.x;
    if (i >= NPIX) return;
    lab[i] = (prob[i] > 0.5f) ? i : 0;
}

__global__ void k_merge(const float* __restrict__ prob, int* __restrict__ lab) {
    int i = blockIdx.x * blockDim.x + threadIdx.x;
    if (i >= NPIX) return;
    if (!(prob[i] > 0.5f)) return;
    int x = i & (W - 1);
    int y = i >> 11;

    bool w_fg = (x > 0) && (prob[i - 1] > 0.5f);
    if (w_fg) unite(lab, i, i - 1);
    if (y > 0) {
        // If west is fg+connected, the NW and N links are implied by the
        // west pixel's own N-union and the NW pixel's NE-union (NE unions
        // are never skipped). Only NE must always be checked.
        if (!w_fg) {
            if (x > 0 && prob[i - W - 1] > 0.5f) unite(lab, i, i - W - 1);
            if (prob[i - W] > 0.5f) unite(lab, i, i - W);
        }
        if (x < W - 1 && prob[i - W + 1] > 0.5f) unite(lab, i, i - W + 1);
    }
}

__global__ void k_compress(const float* __restrict__ prob, int* __restrict__ lab) {
    int i = blockIdx.x * blockDim.x + threadIdx.x;
    if (i >= NPIX) return;
    if (prob[i] > 0.5f) {
        // In-place root write is safe: replacing a label with its root only
        // shortens other threads' chase paths; lab[root] == root is stable.
        lab[i] = find_root(lab, i);
    }
}

__global__ void k_final(const float* __restrict__ prob, int* __restrict__ lab) {
    int i = blockIdx.x * blockDim.x + threadIdx.x;
    if (i >= NPIX) return;
    lab[i] = (prob[i] > 0.5f) ? lab[i] + 1 : 0;
}

extern "C" void kernel_launch(void* const* d_in, const int* in_sizes, int n_in,
                              void* d_out, int out_size, void* d_ws, size_t ws_size,
                              hipStream_t stream) {
    const float* prob = (const float*)d_in[0];
    int* lab = (int*)d_out;

    const int block = 256;
    const int grid = (NPIX + block - 1) / block;

    k_init<<<grid, block, 0, stream>>>(prob, lab);
    k_merge<<<grid, block, 0, stream>>>(prob, lab);
    k_compress<<<grid, block, 0, stream>>>(prob, lab);
    k_final<<<grid, block, 0, stream>>>(prob, lab);
}

// Round 2
// 146.735 us; speedup vs baseline: 2.1443x; 2.1443x over previous
//
#include <hip/hip_runtime.h>

// 8-connected CCL on a 2048x2048 mask (prob > 0.5).
// Output int32: (component min flat index)+1 for fg, 0 for bg.
//
// Two-level union-find:
//   1. k_local  : per 64x64 tile, full union-find in LDS; write each pixel's
//                 parent = global index of its TILE root (1-based encoding).
//   2. k_border : cross-tile causal unions (W/NW/N/NE) for tile-edge pixels
//                 only (~200K unions instead of ~4M), global atomicMin.
//   3. k_compress: every pixel chases to its true root; since parents are
//                 stored 1-based (0 = background), the compressed value IS
//                 the final output (min_index+1 / 0). No separate final pass.

#define H 2048
#define W 2048
#define NPIX (H * W)
#define TS 64

// ---------- global union-find, 1-based parent encoding ----------
// lab[i] == 0   : background
// lab[i] == p+1 : parent pointer to pixel p (root iff p == i)

__device__ __forceinline__ int gfind(const int* __restrict__ L, int a) {
    int n = L[a];
    while (n != a + 1) { a = n - 1; n = L[a]; }
    return a;
}

__device__ __forceinline__ void gunite(int* L, int a, int b) {
    while (true) {
        a = gfind(L, a);
        b = gfind(L, b);
        if (a == b) return;
        if (a > b) { int t = a; a = b; b = t; }
        int old = atomicMin(&L[b], a + 1);
        if (old == b + 1) return;  // attached
        b = old - 1;               // raced; retry from observed parent
    }
}

// ---------- local (LDS) union-find, 0-based, -1 = background ----------
__device__ __forceinline__ int lfind(volatile int* L, int a) {
    int n = L[a];
    while (n != a) { a = n; n = L[a]; }
    return a;
}

__device__ __forceinline__ void lunite(int* L, int a, int b) {
    volatile int* Lv = L;
    while (true) {
        a = lfind(Lv, a);
        b = lfind(Lv, b);
        if (a == b) return;
        if (a > b) { int t = a; a = b; b = t; }
        int old = atomicMin(&L[b], a);
        if (old == b) return;
        b = old;
    }
}

__global__ __launch_bounds__(256)
void k_local(const float* __restrict__ prob, int* __restrict__ lab) {
    __shared__ int slab[TS * TS];
    const int x0 = blockIdx.x * TS, y0 = blockIdx.y * TS;
    const int lx = threadIdx.x;   // 0..63
    const int ty = threadIdx.y;   // 0..3

    // init: fg -> own local index, bg -> -1 (sign is stable under unions)
    #pragma unroll
    for (int k = 0; k < 16; ++k) {
        int ly = ty + (k << 2);
        int li = ly * TS + lx;
        bool fg = prob[(y0 + ly) * W + x0 + lx] > 0.5f;
        slab[li] = fg ? li : -1;
    }
    __syncthreads();

    // intra-tile causal unions. If west is fg, the NW/N links are implied
    // (west's own N-union / west's NE-union); NE is never skipped.
    #pragma unroll 1
    for (int k = 0; k < 16; ++k) {
        int ly = ty + (k << 2);
        int li = ly * TS + lx;
        if (slab[li] < 0) continue;
        bool wfg = (lx > 0) && (slab[li - 1] >= 0);
        if (wfg) lunite(slab, li, li - 1);
        if (ly > 0) {
            if (!wfg) {
                if (lx > 0 && slab[li - TS - 1] >= 0) lunite(slab, li, li - TS - 1);
                if (slab[li - TS] >= 0) lunite(slab, li, li - TS);
            }
            if (lx < TS - 1 && slab[li - TS + 1] >= 0) lunite(slab, li, li - TS + 1);
        }
    }
    __syncthreads();

    // flatten: each pixel's global parent = global index of its tile root
    #pragma unroll 1
    for (int k = 0; k < 16; ++k) {
        int ly = ty + (k << 2);
        int li = ly * TS + lx;
        int out = 0;
        if (slab[li] >= 0) {
            int r = lfind(slab, li);
            out = (y0 + (r >> 6)) * W + (x0 + (r & 63)) + 1;
        }
        lab[(y0 + ly) * W + x0 + lx] = out;
    }
}

// Cross-tile unions. Three segments of 65536 threads each:
//   seg 0: tile-left columns  (lx==0)   -> W, NW cross links
//   seg 1: tile-right columns (lx==63)  -> NE cross link
//   seg 2: tile-top rows      (ly==0)   -> NW, N, NE (+W at lx==0) cross links
// Overlap pixels appear in two segments; duplicate unions are harmless.
__global__ __launch_bounds__(256)
void k_border(int* __restrict__ lab) {
    int tid = blockIdx.x * blockDim.x + threadIdx.x;
    int seg = tid >> 16;
    int r = tid & 65535;
    int x, y;
    if (seg == 0)      { x = (r & 31) << 6;        y = r >> 5; }
    else if (seg == 1) { x = ((r & 31) << 6) + 63; y = r >> 5; }
    else               { x = r & (W - 1);          y = (r >> 11) << 6; }

    int i = y * W + x;
    if (lab[i] == 0) return;  // bg (fg labels are always >= 1)
    int lx = x & (TS - 1), ly = y & (TS - 1);

    if (x > 0 && lx == 0 && lab[i - 1]) gunite(lab, i, i - 1);
    if (x > 0 && y > 0 && (lx == 0 || ly == 0) && lab[i - W - 1]) gunite(lab, i, i - W - 1);
    if (y > 0 && ly == 0 && lab[i - W]) gunite(lab, i, i - W);
    if (y > 0 && x < W - 1 && (ly == 0 || lx == 63) && lab[i - W + 1]) gunite(lab, i, i - W + 1);
}

// Compress to final output. 1-based encoding means the compressed parent
// value (root+1) is exactly the reference output; bg stays 0. Concurrent
// in-place writes only shorten other threads' chase paths.
__global__ __launch_bounds__(256)
void k_compress(int* __restrict__ lab) {
    int i = blockIdx.x * blockDim.x + threadIdx.x;
    if (i >= NPIX) return;
    int v = lab[i];
    if (v == 0 || v == i + 1) return;  // bg or already root
    int r = gfind(lab, v - 1);
    lab[i] = r + 1;
}

extern "C" void kernel_launch(void* const* d_in, const int* in_sizes, int n_in,
                              void* d_out, int out_size, void* d_ws, size_t ws_size,
                              hipStream_t stream) {
    const float* prob = (const float*)d_in[0];
    int* lab = (int*)d_out;

    dim3 lgrid(W / TS, H / TS);
    dim3 lblock(TS, 4);
    k_local<<<lgrid, lblock, 0, stream>>>(prob, lab);

    const int nborder = 3 * 65536;
    k_border<<<nborder / 256, 256, 0, stream>>>(lab);

    k_compress<<<NPIX / 256, 256, 0, stream>>>(lab);
}